// Round 13
// baseline (655.704 us; speedup 1.0000x reference)
//
#include <hip/hip_runtime.h>
#include <stdint.h>

typedef unsigned short v2u __attribute__((ext_vector_type(2)));

#define TM 64
#define TN 64
#define BK 32        // k elements per tile step
#define KP 16        // packed k-pairs per tile step

__device__ __forceinline__ uint32_t rnd_bf16(float f) {
    uint32_t u = __builtin_bit_cast(uint32_t, f);
    return (u + 0x7FFFu + ((u >> 16) & 1u)) >> 16;   // RNE f32 -> bf16 (finite)
}
__device__ __forceinline__ float bf16_to_f32(uint32_t bits16) {
    return __builtin_bit_cast(float, bits16 << 16);
}

// ROUND 13. Model pinned: VOP3P (pk_add_u16, dot2_f32_bf16) is HALF-RATE on
// gfx950 (busy 537us ~= 4cyc/MAC core 437 + 10% staging; r11/r12 concur).
// 4 cyc/MAC is the VALU floor (scalar VOP2 alternative ties). Remaining
// levers are idle (106us) + staging. This round: TM 128->64 => 2048 blocks
// = 8 blocks/CU (VGPR 52 < 64 cap), to overlap barrier drains across more
// co-resident blocks. Inner pair-op sequence unchanged (bit-verified).
__global__ __launch_bounds__(256, 8)
void fpma_gemm(const uint32_t* __restrict__ X,   // [M,K] f32 bits (bf16-exact)
               const uint32_t* __restrict__ Wt,  // [N,K] f32 bits (bf16-exact)
               const float*    __restrict__ Bias,// [N]   f32 (bf16-exact)
               float* __restrict__ Out,          // [M,N] f32 (bf16-valued)
               int M, int N, int K)
{
    __shared__ uint32_t Xp[KP][TM];  // packed (x - 0x3F80) per half, mag-floored
    __shared__ uint32_t Wr[KP][TN];  // packed w bits, mag-floored

    const int tid = threadIdx.x;
    const int tx  = tid & 15;            // n-fragment selector (4 cols)
    const int ty  = tid >> 4;            // m-fragment selector (4 rows)
    const int m0  = blockIdx.y * TM;
    const int n0  = blockIdx.x * TN;

    // staging roles: 64 rows x 32 k, 8 f32 per thread, for each operand
    const int sr = tid & 63;             // row within tile
    const int sq = tid >> 6;             // 0..3: k-quarter (8 f32 = 4 pairs)

    const uint32_t* xptr = X  + (size_t)(m0 + sr) * K + sq * 8;
    const uint32_t* wptr = Wt + (size_t)(n0 + sr) * K + sq * 8;

    float acc[4][4];
    #pragma unroll
    for (int i = 0; i < 4; ++i)
        #pragma unroll
        for (int j = 0; j < 4; ++j) acc[i][j] = 0.0f;

    const float ones_pair = __builtin_bit_cast(float, 0x3F803F80u); // {1,1} bf16

    // prefetch k-step 0 (8 f32 per operand per thread)
    uint4 ax0 = *(const uint4*)(xptr);
    uint4 ax1 = *(const uint4*)(xptr + 4);
    uint4 aw0 = *(const uint4*)(wptr);
    uint4 aw1 = *(const uint4*)(wptr + 4);

    const v2u vfloor = {0x2000, 0x2000};
    const int ksteps = K / BK;
    for (int kt = 0; kt < ksteps; ++kt) {
        __syncthreads();   // previous compute done before overwriting LDS
        {
            uint32_t xd[8] = {ax0.x,ax0.y,ax0.z,ax0.w, ax1.x,ax1.y,ax1.z,ax1.w};
            uint32_t wd[8] = {aw0.x,aw0.y,aw0.z,aw0.w, aw1.x,aw1.y,aw1.z,aw1.w};
            #pragma unroll
            for (int d = 0; d < 4; ++d) {
                const int kp = sq * 4 + d;
                uint32_t u = (xd[2*d] >> 16) | (xd[2*d+1] & 0xFFFF0000u);
                v2u m = __builtin_bit_cast(v2u, u & 0x7FFF7FFFu);
                m = __builtin_elementwise_max(m, vfloor);
                uint32_t c = (u & 0x80008000u) ^ 0xC080C080u;  // sign - 0x3F80
                v2u xp = m + __builtin_bit_cast(v2u, c);       // mod 2^16/half
                Xp[kp][sr] = __builtin_bit_cast(uint32_t, xp);

                uint32_t v = (wd[2*d] >> 16) | (wd[2*d+1] & 0xFFFF0000u);
                v2u wm = __builtin_bit_cast(v2u, v & 0x7FFF7FFFu);
                wm = __builtin_elementwise_max(wm, vfloor);
                Wr[kp][sr] = __builtin_bit_cast(uint32_t, wm) | (v & 0x80008000u);
            }
        }
        __syncthreads();
        if (kt + 1 < ksteps) {          // prefetch next strip; overlaps compute
            xptr += BK; wptr += BK;
            ax0 = *(const uint4*)(xptr);
            ax1 = *(const uint4*)(xptr + 4);
            aw0 = *(const uint4*)(wptr);
            aw1 = *(const uint4*)(wptr + 4);
        }

        #pragma unroll 2
        for (int kp = 0; kp < KP; ++kp) {
            uint32_t xf[4], wf[4];
            // X: 16 lanes per ty share one address -> broadcast; W: tx*4
            // addresses -> 2-way bank aliasing only (free, m136)
            uint4 qa = *(const uint4*)&Xp[kp][ty * 4];
            xf[0]=qa.x; xf[1]=qa.y; xf[2]=qa.z; xf[3]=qa.w;
            uint4 qc = *(const uint4*)&Wr[kp][tx * 4];
            wf[0]=qc.x; wf[1]=qc.y; wf[2]=qc.z; wf[3]=qc.w;

            #pragma unroll
            for (int i = 0; i < 4; ++i) {
                #pragma unroll
                for (int j = 0; j < 4; ++j) {
                    v2u u = __builtin_bit_cast(v2u, xf[i]) +
                            __builtin_bit_cast(v2u, wf[j]);        // v_pk_add_u16
                    float up = __builtin_bit_cast(float, u);       // signed bf16 pair
                    asm("v_dot2_f32_bf16 %0, %1, %2, %0"
                        : "+v"(acc[i][j]) : "v"(up), "v"(ones_pair));
                }
            }
        }
    }

    // epilogue: out = f32( bf16( f32(bf16(acc)) + bias ) )
    float4 bl = *(const float4*)&Bias[n0 + tx * 4];
    float bf[4] = {bl.x, bl.y, bl.z, bl.w};
    #pragma unroll
    for (int i = 0; i < 4; ++i) {
        float o[4];
        #pragma unroll
        for (int j = 0; j < 4; ++j)
            o[j] = bf16_to_f32(rnd_bf16(bf16_to_f32(rnd_bf16(acc[i][j])) + bf[j]));
        const size_t row = (size_t)(m0 + ty * 4 + i) * N;
        *(float4*)&Out[row + n0 + tx * 4] = make_float4(o[0], o[1], o[2], o[3]);
    }
}

extern "C" void kernel_launch(void* const* d_in, const int* in_sizes, int n_in,
                              void* d_out, int out_size, void* d_ws, size_t ws_size,
                              hipStream_t stream) {
    (void)n_in; (void)d_ws; (void)ws_size; (void)out_size;
    const uint32_t* X = (const uint32_t*)d_in[0];   // f32 words (bf16-exact)
    const uint32_t* W = (const uint32_t*)d_in[1];
    const float*    B = (const float*)d_in[2];
    float* O = (float*)d_out;                       // f32 out (bf16-valued)

    int N = in_sizes[2];                       // bias [1,N], elements
    int K = (N > 0) ? in_sizes[1] / N : 0;     // weight [N,K]
    int M = (K > 0) ? in_sizes[0] / K : 0;     // input [M,K]
    if (N <= 0 || K <= 0 || M <= 0 ||
        (long long)N * K != (long long)in_sizes[1] ||
        (long long)M * K != (long long)in_sizes[0] ||
        (M % TM) || (N % TN) || (K % BK)) {
        M = 4096; K = 2048; N = 2048;          // documented problem shape
    }

    dim3 grid(N / TN, M / TM);
    fpma_gemm<<<grid, 256, 0, stream>>>(X, W, B, O, M, N, K);
}

// Round 14
// 638.473 us; speedup vs baseline: 1.0270x; 1.0270x over previous
//
#include <hip/hip_runtime.h>
#include <stdint.h>

typedef unsigned short v2u __attribute__((ext_vector_type(2)));

#define TM 128
#define TN 64
#define BK 32        // k elements per tile step
#define KP 16        // packed k-pairs per tile step

__device__ __forceinline__ uint32_t rnd_bf16(float f) {
    uint32_t u = __builtin_bit_cast(uint32_t, f);
    return (u + 0x7FFFu + ((u >> 16) & 1u)) >> 16;   // RNE f32 -> bf16 (finite)
}
__device__ __forceinline__ float bf16_to_f32(uint32_t bits16) {
    return __builtin_bit_cast(float, bits16 << 16);
}

// ROUND 14. r12 (TM128/TN64, 638us) is the best point; r13 showed idle is not
// occupancy-curable (Occ 31->56%, idle flat). The stall is the per-iteration
// 2-barrier rhythm: vmcnt drain -> stage write -> barrier -> compute. Fix:
// DOUBLE-BUFFERED LDS, ONE barrier/iter. iter kt: issue loads(kt+1); compute
// from buf[kt&1]; write buf[1-(kt&1)]; barrier. Reads of the written buffer
// all finished before the PREVIOUS barrier => single barrier is sufficient.
// Inner pair-op sequence unchanged (v_pk_add_u16 fold + v_dot2_f32_bf16,
// bit-verified r10-r13). LDS 24 KB => 4 blocks/CU.
__global__ __launch_bounds__(256, 4)
void fpma_gemm(const uint32_t* __restrict__ X,   // [M,K] f32 bits (bf16-exact)
               const uint32_t* __restrict__ Wt,  // [N,K] f32 bits (bf16-exact)
               const float*    __restrict__ Bias,// [N]   f32 (bf16-exact)
               float* __restrict__ Out,          // [M,N] f32 (bf16-valued)
               int M, int N, int K)
{
    __shared__ uint32_t Xp[2][KP][TM];  // packed (x - 0x3F80)/half, mag-floored
    __shared__ uint32_t Wr[2][KP][TN];  // packed w bits, mag-floored

    const int tid = threadIdx.x;
    const int tx  = tid & 15;            // n-fragment selector (4 cols)
    const int ty  = tid >> 4;            // m-fragment selector (8 rows)
    const int m0  = blockIdx.y * TM;
    const int n0  = blockIdx.x * TN;

    // X staging: 128 rows x 32 k, 16 f32/thread. W: 64 rows x 32 k, 8 f32/thr.
    const int xr  = tid & 127;
    const int xh  = tid >> 7;            // 0..1: k-half
    const int wr_ = tid & 63;
    const int wq  = tid >> 6;            // 0..3: k-quarter

    const uint32_t* xptr = X  + (size_t)(m0 + xr) * K + xh * 16;
    const uint32_t* wptr = Wt + (size_t)(n0 + wr_) * K + wq * 8;

    float acc[8][4];
    #pragma unroll
    for (int i = 0; i < 8; ++i)
        #pragma unroll
        for (int j = 0; j < 4; ++j) acc[i][j] = 0.0f;

    const float ones_pair = __builtin_bit_cast(float, 0x3F803F80u); // {1,1} bf16
    const v2u vfloor = {0x2000, 0x2000};

    uint4 ax0, ax1, ax2, ax3, aw0, aw1;
    // ---- preload tile 0, stage into buf 0 ----
    ax0 = *(const uint4*)(xptr);
    ax1 = *(const uint4*)(xptr + 4);
    ax2 = *(const uint4*)(xptr + 8);
    ax3 = *(const uint4*)(xptr + 12);
    aw0 = *(const uint4*)(wptr);
    aw1 = *(const uint4*)(wptr + 4);
    {
        uint32_t xd[16] = {ax0.x,ax0.y,ax0.z,ax0.w, ax1.x,ax1.y,ax1.z,ax1.w,
                           ax2.x,ax2.y,ax2.z,ax2.w, ax3.x,ax3.y,ax3.z,ax3.w};
        #pragma unroll
        for (int d = 0; d < 8; ++d) {
            const int kp = xh * 8 + d;
            uint32_t u = (xd[2*d] >> 16) | (xd[2*d+1] & 0xFFFF0000u);
            v2u m = __builtin_bit_cast(v2u, u & 0x7FFF7FFFu);
            m = __builtin_elementwise_max(m, vfloor);
            uint32_t c = (u & 0x80008000u) ^ 0xC080C080u;  // sign - 0x3F80
            v2u xp = m + __builtin_bit_cast(v2u, c);
            Xp[0][kp][xr] = __builtin_bit_cast(uint32_t, xp);
        }
        uint32_t wd[8] = {aw0.x,aw0.y,aw0.z,aw0.w, aw1.x,aw1.y,aw1.z,aw1.w};
        #pragma unroll
        for (int d = 0; d < 4; ++d) {
            const int kp = wq * 4 + d;
            uint32_t v = (wd[2*d] >> 16) | (wd[2*d+1] & 0xFFFF0000u);
            v2u wm = __builtin_bit_cast(v2u, v & 0x7FFF7FFFu);
            wm = __builtin_elementwise_max(wm, vfloor);
            Wr[0][kp][wr_] = __builtin_bit_cast(uint32_t, wm) | (v & 0x80008000u);
        }
    }
    __syncthreads();

    const int ksteps = K / BK;
    for (int kt = 0; kt < ksteps; ++kt) {
        const int cur = kt & 1;
        const bool more = (kt + 1 < ksteps);
        if (more) {                      // issue loads for tile kt+1 NOW;
            xptr += BK; wptr += BK;      // they overlap the whole compute phase
            ax0 = *(const uint4*)(xptr);
            ax1 = *(const uint4*)(xptr + 4);
            ax2 = *(const uint4*)(xptr + 8);
            ax3 = *(const uint4*)(xptr + 12);
            aw0 = *(const uint4*)(wptr);
            aw1 = *(const uint4*)(wptr + 4);
        }

        #pragma unroll 1                 // bound I-cache footprint
        for (int kp = 0; kp < KP; ++kp) {
            uint32_t xf[8], wf[4];
            // X: 16 lanes/ty share an address -> broadcast; W: 2-way alias (free)
            uint4 qa = ((const uint4*)&Xp[cur][kp][ty * 8])[0];
            uint4 qb = ((const uint4*)&Xp[cur][kp][ty * 8])[1];
            xf[0]=qa.x; xf[1]=qa.y; xf[2]=qa.z; xf[3]=qa.w;
            xf[4]=qb.x; xf[5]=qb.y; xf[6]=qb.z; xf[7]=qb.w;
            uint4 qc = *(const uint4*)&Wr[cur][kp][tx * 4];
            wf[0]=qc.x; wf[1]=qc.y; wf[2]=qc.z; wf[3]=qc.w;

            #pragma unroll
            for (int i = 0; i < 8; ++i) {
                #pragma unroll
                for (int j = 0; j < 4; ++j) {
                    v2u u = __builtin_bit_cast(v2u, xf[i]) +
                            __builtin_bit_cast(v2u, wf[j]);        // v_pk_add_u16
                    float up = __builtin_bit_cast(float, u);       // signed bf16 pair
                    asm("v_dot2_f32_bf16 %0, %1, %2, %0"
                        : "+v"(acc[i][j]) : "v"(up), "v"(ones_pair));
                }
            }
        }

        if (more) {                      // stage tile kt+1 into the other buffer
            const int nxt = cur ^ 1;
            uint32_t xd[16] = {ax0.x,ax0.y,ax0.z,ax0.w, ax1.x,ax1.y,ax1.z,ax1.w,
                               ax2.x,ax2.y,ax2.z,ax2.w, ax3.x,ax3.y,ax3.z,ax3.w};
            #pragma unroll
            for (int d = 0; d < 8; ++d) {
                const int kp = xh * 8 + d;
                uint32_t u = (xd[2*d] >> 16) | (xd[2*d+1] & 0xFFFF0000u);
                v2u m = __builtin_bit_cast(v2u, u & 0x7FFF7FFFu);
                m = __builtin_elementwise_max(m, vfloor);
                uint32_t c = (u & 0x80008000u) ^ 0xC080C080u;
                v2u xp = m + __builtin_bit_cast(v2u, c);
                Xp[nxt][kp][xr] = __builtin_bit_cast(uint32_t, xp);
            }
            uint32_t wd[8] = {aw0.x,aw0.y,aw0.z,aw0.w, aw1.x,aw1.y,aw1.z,aw1.w};
            #pragma unroll
            for (int d = 0; d < 4; ++d) {
                const int kp = wq * 4 + d;
                uint32_t v = (wd[2*d] >> 16) | (wd[2*d+1] & 0xFFFF0000u);
                v2u wm = __builtin_bit_cast(v2u, v & 0x7FFF7FFFu);
                wm = __builtin_elementwise_max(wm, vfloor);
                Wr[nxt][kp][wr_] = __builtin_bit_cast(uint32_t, wm) | (v & 0x80008000u);
            }
        }
        __syncthreads();                 // single barrier per iteration
    }

    // epilogue: out = f32( bf16( f32(bf16(acc)) + bias ) )
    float4 bl = *(const float4*)&Bias[n0 + tx * 4];
    float bf[4] = {bl.x, bl.y, bl.z, bl.w};
    #pragma unroll
    for (int i = 0; i < 8; ++i) {
        float o[4];
        #pragma unroll
        for (int j = 0; j < 4; ++j)
            o[j] = bf16_to_f32(rnd_bf16(bf16_to_f32(rnd_bf16(acc[i][j])) + bf[j]));
        const size_t row = (size_t)(m0 + ty * 8 + i) * N;
        *(float4*)&Out[row + n0 + tx * 4] = make_float4(o[0], o[1], o[2], o[3]);
    }
}

extern "C" void kernel_launch(void* const* d_in, const int* in_sizes, int n_in,
                              void* d_out, int out_size, void* d_ws, size_t ws_size,
                              hipStream_t stream) {
    (void)n_in; (void)d_ws; (void)ws_size; (void)out_size;
    const uint32_t* X = (const uint32_t*)d_in[0];   // f32 words (bf16-exact)
    const uint32_t* W = (const uint32_t*)d_in[1];
    const float*    B = (const float*)d_in[2];
    float* O = (float*)d_out;                       // f32 out (bf16-valued)

    int N = in_sizes[2];                       // bias [1,N], elements
    int K = (N > 0) ? in_sizes[1] / N : 0;     // weight [N,K]
    int M = (K > 0) ? in_sizes[0] / K : 0;     // input [M,K]
    if (N <= 0 || K <= 0 || M <= 0 ||
        (long long)N * K != (long long)in_sizes[1] ||
        (long long)M * K != (long long)in_sizes[0] ||
        (M % TM) || (N % TN) || (K % BK)) {
        M = 4096; K = 2048; N = 2048;          // documented problem shape
    }

    dim3 grid(N / TN, M / TM);
    fpma_gemm<<<grid, 256, 0, stream>>>(X, W, B, O, M, N, K);
}